// Round 11
// baseline (442.697 us; speedup 1.0000x reference)
//
#include <hip/hip_runtime.h>
#include <hip/hip_bf16.h>
#include <cstdint>
#include <cstddef>

#define NN     8192
#define INF_   256
#define OUTF   128
#define ALPHA  0.2f
#define LOG2E  1.4426950408889634f
#define JSPLIT 8
#define CHUNK  (NN / JSPLIT)   // 1024 j per block

typedef __bf16 bf16;
typedef unsigned int u32;
typedef unsigned long long u64;
typedef __attribute__((ext_vector_type(8))) __bf16 bf16x8;
typedef __attribute__((ext_vector_type(4))) float f32x4;
typedef __attribute__((ext_vector_type(4))) unsigned int u32x4;
typedef __attribute__((ext_vector_type(8))) unsigned short u16x8;
typedef __attribute__((ext_vector_type(4))) unsigned short u16x4;

// Input dtypes hardcoded fp32 (+ fp32 out): confirmed by runtime detector over
// R2-R10 (flag==1 every round, absmax stable at 1.95e-3 with fp32 stores).

static __device__ __forceinline__ void load4(const float* p, bf16* d) {
    const f32x4 v = *(const f32x4*)p;
    #pragma unroll
    for (int t = 0; t < 4; ++t) d[t] = (bf16)v[t];
}

// ---------------------------------------------------------------------------
// trans transpose: TT[n][k] = bf16(trans[k][n]).
// ---------------------------------------------------------------------------
__global__ void gat_tt(const float* __restrict__ trans, bf16* __restrict__ TT)
{
    const int n = blockIdx.x;      // 0..127
    const int k = threadIdx.x;     // 0..255
    TT[n * INF_ + k] = (bf16)trans[k * OUTF + n];
}

// ---------------------------------------------------------------------------
// Projection: h = x @ trans, 16 rows/block (grid 512 -> 2 blocks/CU).
// x staged in LDS; TT b-frags from L1/L2 (64 KB hot). Outputs:
//   HTt tiled HTt[i>>5][n][i&31]
//   E1p/E1n (rows):  exp2(e1*log2e), exp2(ALPHA*e1*log2e)
//   E2p/E2n (cols):  exp2(e2*log2e), exp2(ALPHA*e2*log2e)
// attn then uses exp2(lrelu(e1+e2)) == max(E1p*E2p, E1n*E2n)  (exp2 monotone)
// ---------------------------------------------------------------------------
__global__ __launch_bounds__(256, 2)
void gat_proj(const float* __restrict__ x, const bf16* __restrict__ TT,
              const float* __restrict__ aw,
              bf16* __restrict__ HTt, float* __restrict__ E1p, float* __restrict__ E1n,
              float* __restrict__ E2p, float* __restrict__ E2n)
{
    __shared__ bf16  xs[16][264];
    __shared__ float hl[16][129];

    const int tid  = threadIdx.x;
    const int wave = tid >> 6;
    const int lane = tid & 63;
    const int m    = lane & 15;
    const int q    = lane >> 4;
    const int i0   = blockIdx.x * 16;
    const int n0   = wave * 32;

    // stage x: 16 rows x 256 cols, coalesced, cvt to bf16
    #pragma unroll
    for (int it = 0; it < 4; ++it) {
        const int e = it * 1024 + tid * 4;
        bf16 tmp[4];
        load4(x + (size_t)i0 * INF_ + e, tmp);
        *(u16x4*)&xs[e >> 8][e & 255] = *(u16x4*)tmp;
    }
    __syncthreads();

    f32x4 acc0 = {}, acc1 = {};
    #pragma unroll
    for (int ks = 0; ks < INF_; ks += 32) {
        const bf16x8 a  = *(const bf16x8*)&xs[m][ks + q * 8];          // A[m][k]
        const bf16x8 b0 = *(const bf16x8*)(TT + (n0 + m) * INF_ + ks + q * 8);
        const bf16x8 b1 = *(const bf16x8*)(TT + (n0 + 16 + m) * INF_ + ks + q * 8);
        acc0 = __builtin_amdgcn_mfma_f32_16x16x32_bf16(a, b0, acc0, 0, 0, 0);
        acc1 = __builtin_amdgcn_mfma_f32_16x16x32_bf16(a, b1, acc1, 0, 0, 0);
    }

    // C/D layout: col = lane&15, row = q*4 + reg
    #pragma unroll
    for (int r = 0; r < 4; ++r) {
        hl[q * 4 + r][n0 + m]      = acc0[r];
        hl[q * 4 + r][n0 + 16 + m] = acc1[r];
    }
    __syncthreads();

    {   // e1/e2 dot products -> exp2 forms
        const int r = tid >> 4, tn = tid & 15;
        float s1 = 0.f, s2 = 0.f;
        #pragma unroll
        for (int u = 0; u < 8; ++u) {
            const float hv = hl[r][tn * 8 + u];
            s1 += hv * aw[tn * 8 + u];
            s2 += hv * aw[OUTF + tn * 8 + u];
        }
        #pragma unroll
        for (int d = 1; d < 16; d <<= 1) {
            s1 += __shfl_xor(s1, d);
            s2 += __shfl_xor(s2, d);
        }
        if (tn == 0) {
            const float a1 = s1 * LOG2E, a2 = s2 * LOG2E;
            E1p[i0 + r] = __builtin_amdgcn_exp2f(a1);
            E1n[i0 + r] = __builtin_amdgcn_exp2f(ALPHA * a1);
            E2p[i0 + r] = __builtin_amdgcn_exp2f(a2);
            E2n[i0 + r] = __builtin_amdgcn_exp2f(ALPHA * a2);
        }
    }

    {   // HTt tiled write: HTt[i>>5][n][i&31]; this block covers half a 32-tile
        const int n = tid >> 1, ih = tid & 1;
        u16x8 pk;
        #pragma unroll
        for (int v = 0; v < 8; ++v)
            pk[v] = __builtin_bit_cast(unsigned short, (bf16)hl[ih * 8 + v][n]);
        bf16* base = HTt + (size_t)(i0 >> 5) * 4096 + n * 32
                   + ((i0 >> 4) & 1) * 16 + ih * 8;
        *(u16x8*)base = pk;
    }
}

// ---------------------------------------------------------------------------
// FUSED adj-stream + masked-softmax-attention partials (R8 structure — best
// measured). Grid 1024 = 4 blocks/CU, no LDS, no barriers, plain loads;
// 16 waves/CU TLP hides adj latency. NEW: transcendental-free P-build via
//   p = mask ? max(E1p*E2p[j], E1n*E2n[j]) : 0     (== exp2(lrelu(e1+e2)))
// and #pragma unroll 2 on the window loop (compiler-visible cross-window ILP).
// jc = bid & 7 pins each XCD to one HTt/E2 j-slice (L2-resident).
// ---------------------------------------------------------------------------
__global__ __launch_bounds__(256, 4)
void gat_attn(const int* __restrict__ adj, const bf16* __restrict__ HTt,
              const float* __restrict__ E1p, const float* __restrict__ E1n,
              const float* __restrict__ E2p, const float* __restrict__ E2n,
              float* __restrict__ numP, float* __restrict__ denP)
{
    const int tid  = threadIdx.x;
    const int wave = tid >> 6;
    const int lane = tid & 63;
    const int m    = lane & 15;
    const int q    = lane >> 4;
    const int jc   = blockIdx.x & (JSPLIT - 1);
    const int ig   = blockIdx.x / JSPLIT;
    const int rbase = ig * 64 + wave * 16;
    const int j0    = jc * CHUNK;

    const float e1p = E1p[rbase + m];
    const float e1n = E1n[rbase + m];
    const int*   ap = adj + (size_t)rbase * NN + j0 + lane;
    const float* pp = E2p + j0 + q * 8;
    const float* pn = E2n + j0 + q * 8;
    const bf16*  pb = HTt + (size_t)(j0 >> 5) * 4096 + m * 32 + q * 8;

    f32x4 acc[8] = {};
    float rs = 0.f;

    #pragma unroll 2
    for (int w = 0; w < CHUNK / 64; ++w) {          // 16 windows of 64 j
        // stream this wave's 16 rows x 64 j of adj (bit j = lane for ballot)
        int v[16];
        #pragma unroll
        for (int r = 0; r < 16; ++r)
            v[r] = ap[(size_t)r * NN + w * 64];

        // pack: row r -> 64-bit mask; park row r's mask in lane r
        u32 mlo = 0, mhi = 0;
        #pragma unroll
        for (int r = 0; r < 16; ++r) {
            const u64 b = __ballot(v[r] != 0);
            if (lane == r) { mlo = (u32)b; mhi = (u32)(b >> 32); }
        }
        // lane (m,q) pulls row m's mask halves
        const u32 wlo = __shfl(mlo, m);
        const u32 whi = __shfl(mhi, m);

        #pragma unroll
        for (int h = 0; h < 2; ++h) {               // two 32-j MFMA steps
            const u32 wb = h ? whi : wlo;
            const int j  = w * 64 + h * 32;
            const f32x4 p2a = *(const f32x4*)(pp + j);
            const f32x4 p2b = *(const f32x4*)(pp + j + 4);
            const f32x4 n2a = *(const f32x4*)(pn + j);
            const f32x4 n2b = *(const f32x4*)(pn + j + 4);

            bf16x8 af;   // A-fragment: A[m][k=q*8+t]
            #pragma unroll
            for (int t = 0; t < 4; ++t) {
                float p = fmaxf(e1p * p2a[t], e1n * n2a[t]);
                p = ((wb >> (q * 8 + t)) & 1u) ? p : 0.f;
                rs += p;
                af[t] = (bf16)p;
            }
            #pragma unroll
            for (int t = 0; t < 4; ++t) {
                float p = fmaxf(e1p * p2b[t], e1n * n2b[t]);
                p = ((wb >> (q * 8 + 4 + t)) & 1u) ? p : 0.f;
                rs += p;
                af[4 + t] = (bf16)p;
            }

            const bf16* pbs = pb + (size_t)(j >> 5) * 4096;
            #pragma unroll
            for (int t = 0; t < 8; ++t) {
                const bf16x8 b = __builtin_bit_cast(bf16x8, *(const u32x4*)(pbs + t * 512));
                acc[t] = __builtin_amdgcn_mfma_f32_16x16x32_bf16(af, b, acc[t], 0, 0, 0);
            }
        }
    }

    // row-sum: lanes {m, m+16, m+32, m+48} hold the 4 q-slices of row m
    rs += __shfl_xor(rs, 16);
    rs += __shfl_xor(rs, 32);
    if (lane < 16) denP[(size_t)jc * NN + rbase + m] = rs;

    // C/D layout: col = lane&15, row = q*4 + r -> unique partial slot
    #pragma unroll
    for (int t = 0; t < 8; ++t)
        #pragma unroll
        for (int r = 0; r < 4; ++r)
            numP[((size_t)jc * NN + rbase + q * 4 + r) * OUTF + t * 16 + m] = acc[t][r];
}

// ---------------------------------------------------------------------------
// Finalize: out = elu( (sum_s numP) / (sum_s denP) ), fp32 out.
// ---------------------------------------------------------------------------
__global__ __launch_bounds__(256)
void gat_fin(const float* __restrict__ numP, const float* __restrict__ denP,
             float* __restrict__ outv)
{
    const int g  = blockIdx.x * 256 + threadIdx.x;   // one thread per 4 elems
    const int i  = g >> 5;
    const int c4 = g & 31;
    float d = 0.f;
    f32x4 v = {0.f, 0.f, 0.f, 0.f};
    #pragma unroll
    for (int s = 0; s < JSPLIT; ++s) {
        d += denP[(size_t)s * NN + i];
        const f32x4 u = *(const f32x4*)(numP + ((size_t)s * NN + i) * OUTF + c4 * 4);
        #pragma unroll
        for (int t = 0; t < 4; ++t) v[t] += u[t];
    }
    #pragma unroll
    for (int t = 0; t < 4; ++t) {
        const float u = v[t] / d;
        v[t] = (u > 0.f) ? u : __builtin_amdgcn_exp2f(u * LOG2E) - 1.f;  // elu
    }
    *(f32x4*)(outv + (size_t)i * OUTF + c4 * 4) = v;
}

// ---------------------------------------------------------------------------
extern "C" void kernel_launch(void* const* d_in, const int* in_sizes, int n_in,
                              void* d_out, int out_size, void* d_ws, size_t ws_size,
                              hipStream_t stream)
{
    const float* x     = (const float*)d_in[0];
    const int*   adj   = (const int*)d_in[1];
    const float* trans = (const float*)d_in[2];
    const float* aw    = (const float*)d_in[3];

    // ws layout (bytes):
    // HTt 2MB | E1p/E1n/E2p/E2n 4x32KB | TT 64KB | numP 32MB | denP 256KB
    char* w = (char*)d_ws;
    bf16*  HTt  = (bf16*)w;   w += (size_t)OUTF * NN * 2;
    float* E1p  = (float*)w;  w += NN * 4;
    float* E1n  = (float*)w;  w += NN * 4;
    float* E2p  = (float*)w;  w += NN * 4;
    float* E2n  = (float*)w;  w += NN * 4;
    bf16*  TT   = (bf16*)w;   w += (size_t)OUTF * INF_ * 2;
    float* numP = (float*)w;  w += (size_t)JSPLIT * NN * OUTF * 4;
    float* denP = (float*)w;

    gat_tt<<<OUTF, INF_, 0, stream>>>(trans, TT);

    gat_proj<<<NN / 16, 256, 0, stream>>>(x, TT, aw, HTt, E1p, E1n, E2p, E2n);

    gat_attn<<<(NN / 64) * JSPLIT, 256, 0, stream>>>(adj, HTt, E1p, E1n, E2p, E2n,
                                                     numP, denP);

    gat_fin<<<NN * OUTF / 4 / 256, 256, 0, stream>>>(numP, denP, (float*)d_out);
}

// Round 12
// 442.112 us; speedup vs baseline: 1.0013x; 1.0013x over previous
//
#include <hip/hip_runtime.h>
#include <hip/hip_bf16.h>
#include <cstdint>
#include <cstddef>

#define NN     8192
#define INF_   256
#define OUTF   128
#define ALPHA  0.2f
#define LOG2E  1.4426950408889634f
#define JSPLIT 8
#define CHUNK  (NN / JSPLIT)   // 1024 j per block

typedef __bf16 bf16;
typedef unsigned int u32;
typedef unsigned long long u64;
typedef __attribute__((ext_vector_type(8))) __bf16 bf16x8;
typedef __attribute__((ext_vector_type(4))) float f32x4;
typedef __attribute__((ext_vector_type(4))) unsigned int u32x4;
typedef __attribute__((ext_vector_type(8))) unsigned short u16x8;
typedef __attribute__((ext_vector_type(4))) unsigned short u16x4;

// Input dtypes hardcoded fp32 (+ fp32 out): confirmed by runtime detector over
// R2-R10 (flag==1 every round, absmax stable at 1.95e-3 with fp32 stores).

static __device__ __forceinline__ void load4(const float* p, bf16* d) {
    const f32x4 v = *(const f32x4*)p;
    #pragma unroll
    for (int t = 0; t < 4; ++t) d[t] = (bf16)v[t];
}

// ---------------------------------------------------------------------------
// trans transpose: TT[n][k] = bf16(trans[k][n]).
// ---------------------------------------------------------------------------
__global__ void gat_tt(const float* __restrict__ trans, bf16* __restrict__ TT)
{
    const int n = blockIdx.x;      // 0..127
    const int k = threadIdx.x;     // 0..255
    TT[n * INF_ + k] = (bf16)trans[k * OUTF + n];
}

// ---------------------------------------------------------------------------
// Projection: h = x @ trans, 16 rows/block (grid 512 -> 2 blocks/CU).
// x staged in LDS; TT b-frags from L1/L2 (64 KB hot). Outputs:
//   HTt tiled HTt[i>>5][n][i&31]
//   E1p/E1n (rows):  exp2(e1*log2e), exp2(ALPHA*e1*log2e)
//   E2p/E2n (cols):  exp2(e2*log2e), exp2(ALPHA*e2*log2e)
// attn uses exp2(lrelu(e1+e2)) == max(E1p*E2p, E1n*E2n)  (exp2 monotone)
// ---------------------------------------------------------------------------
__global__ __launch_bounds__(256, 2)
void gat_proj(const float* __restrict__ x, const bf16* __restrict__ TT,
              const float* __restrict__ aw,
              bf16* __restrict__ HTt, float* __restrict__ E1p, float* __restrict__ E1n,
              float* __restrict__ E2p, float* __restrict__ E2n)
{
    __shared__ bf16  xs[16][264];
    __shared__ float hl[16][129];

    const int tid  = threadIdx.x;
    const int wave = tid >> 6;
    const int lane = tid & 63;
    const int m    = lane & 15;
    const int q    = lane >> 4;
    const int i0   = blockIdx.x * 16;
    const int n0   = wave * 32;

    // stage x: 16 rows x 256 cols, coalesced, cvt to bf16
    #pragma unroll
    for (int it = 0; it < 4; ++it) {
        const int e = it * 1024 + tid * 4;
        bf16 tmp[4];
        load4(x + (size_t)i0 * INF_ + e, tmp);
        *(u16x4*)&xs[e >> 8][e & 255] = *(u16x4*)tmp;
    }
    __syncthreads();

    f32x4 acc0 = {}, acc1 = {};
    #pragma unroll
    for (int ks = 0; ks < INF_; ks += 32) {
        const bf16x8 a  = *(const bf16x8*)&xs[m][ks + q * 8];          // A[m][k]
        const bf16x8 b0 = *(const bf16x8*)(TT + (n0 + m) * INF_ + ks + q * 8);
        const bf16x8 b1 = *(const bf16x8*)(TT + (n0 + 16 + m) * INF_ + ks + q * 8);
        acc0 = __builtin_amdgcn_mfma_f32_16x16x32_bf16(a, b0, acc0, 0, 0, 0);
        acc1 = __builtin_amdgcn_mfma_f32_16x16x32_bf16(a, b1, acc1, 0, 0, 0);
    }

    // C/D layout: col = lane&15, row = q*4 + reg
    #pragma unroll
    for (int r = 0; r < 4; ++r) {
        hl[q * 4 + r][n0 + m]      = acc0[r];
        hl[q * 4 + r][n0 + 16 + m] = acc1[r];
    }
    __syncthreads();

    {   // e1/e2 dot products -> exp2 forms
        const int r = tid >> 4, tn = tid & 15;
        float s1 = 0.f, s2 = 0.f;
        #pragma unroll
        for (int u = 0; u < 8; ++u) {
            const float hv = hl[r][tn * 8 + u];
            s1 += hv * aw[tn * 8 + u];
            s2 += hv * aw[OUTF + tn * 8 + u];
        }
        #pragma unroll
        for (int d = 1; d < 16; d <<= 1) {
            s1 += __shfl_xor(s1, d);
            s2 += __shfl_xor(s2, d);
        }
        if (tn == 0) {
            const float a1 = s1 * LOG2E, a2 = s2 * LOG2E;
            E1p[i0 + r] = __builtin_amdgcn_exp2f(a1);
            E1n[i0 + r] = __builtin_amdgcn_exp2f(ALPHA * a1);
            E2p[i0 + r] = __builtin_amdgcn_exp2f(a2);
            E2n[i0 + r] = __builtin_amdgcn_exp2f(ALPHA * a2);
        }
    }

    {   // HTt tiled write: HTt[i>>5][n][i&31]; this block covers half a 32-tile
        const int n = tid >> 1, ih = tid & 1;
        u16x8 pk;
        #pragma unroll
        for (int v = 0; v < 8; ++v)
            pk[v] = __builtin_bit_cast(unsigned short, (bf16)hl[ih * 8 + v][n]);
        bf16* base = HTt + (size_t)(i0 >> 5) * 4096 + n * 32
                   + ((i0 >> 4) & 1) * 16 + ih * 8;
        *(u16x8*)base = pk;
    }
}

// ---------------------------------------------------------------------------
// FUSED adj-stream + masked-softmax-attention partials. R8 structure, but
// 128-j windows: 32 adj loads issued in ONE basic block before any ballot
// use -> 8 KB/wave structurally in flight (2x the R11 MLP; R11 counters
// showed 80% memory-stall at 16 loads/window: VALUBusy 15% matched the
// issue-arithmetic exactly). Grid 1024 = 4 blocks/CU, no LDS, no barriers.
// Per 128-j window:
//   32 coalesced dword loads (rows r=0..15, j halves A/B)
//   32 __ballot -> row-masks parked in lanes; __shfl -> A-fragment lanes
//   4 x 32-j MFMA steps vs L2-hot tiled HTt (8 MFMAs each, all 128 features)
// P-build transcendental-free: p = mask ? max(E1p*E2p[j], E1n*E2n[j]) : 0.
// jc = bid & 7 pins each XCD to one HTt/E2 j-slice (L2-resident).
// ---------------------------------------------------------------------------
__global__ __launch_bounds__(256, 4)
void gat_attn(const int* __restrict__ adj, const bf16* __restrict__ HTt,
              const float* __restrict__ E1p, const float* __restrict__ E1n,
              const float* __restrict__ E2p, const float* __restrict__ E2n,
              float* __restrict__ numP, float* __restrict__ denP)
{
    const int tid  = threadIdx.x;
    const int wave = tid >> 6;
    const int lane = tid & 63;
    const int m    = lane & 15;
    const int q    = lane >> 4;
    const int jc   = blockIdx.x & (JSPLIT - 1);
    const int ig   = blockIdx.x / JSPLIT;
    const int rbase = ig * 64 + wave * 16;
    const int j0    = jc * CHUNK;

    const float e1p = E1p[rbase + m];
    const float e1n = E1n[rbase + m];
    const int*   ap = adj + (size_t)rbase * NN + j0 + lane;
    const float* pp = E2p + j0 + q * 8;
    const float* pn = E2n + j0 + q * 8;
    const bf16*  pb = HTt + (size_t)(j0 >> 5) * 4096 + m * 32 + q * 8;

    f32x4 acc[8] = {};
    float rs = 0.f;

    for (int w = 0; w < CHUNK / 128; ++w) {         // 8 windows of 128 j
        // stream 16 rows x 128 j of adj: 32 independent loads, all in flight
        int va[16], vb[16];
        #pragma unroll
        for (int r = 0; r < 16; ++r)
            va[r] = ap[(size_t)r * NN + w * 128];
        #pragma unroll
        for (int r = 0; r < 16; ++r)
            vb[r] = ap[(size_t)r * NN + w * 128 + 64];

        // pack: row r -> two 64-bit masks; park row r's masks in lane r
        u32 aLo = 0, aHi = 0, bLo = 0, bHi = 0;
        #pragma unroll
        for (int r = 0; r < 16; ++r) {
            const u64 ba = __ballot(va[r] != 0);
            if (lane == r) { aLo = (u32)ba; aHi = (u32)(ba >> 32); }
        }
        #pragma unroll
        for (int r = 0; r < 16; ++r) {
            const u64 bb = __ballot(vb[r] != 0);
            if (lane == r) { bLo = (u32)bb; bHi = (u32)(bb >> 32); }
        }
        // lane (m,q) pulls row m's mask words
        u32 wm[4];
        wm[0] = __shfl(aLo, m);
        wm[1] = __shfl(aHi, m);
        wm[2] = __shfl(bLo, m);
        wm[3] = __shfl(bHi, m);

        #pragma unroll
        for (int h = 0; h < 4; ++h) {               // four 32-j MFMA steps
            const u32 wb = wm[h];
            const int j  = w * 128 + h * 32;
            const f32x4 p2a = *(const f32x4*)(pp + j);
            const f32x4 p2b = *(const f32x4*)(pp + j + 4);
            const f32x4 n2a = *(const f32x4*)(pn + j);
            const f32x4 n2b = *(const f32x4*)(pn + j + 4);

            bf16x8 af;   // A-fragment: A[m][k=q*8+t]
            #pragma unroll
            for (int t = 0; t < 4; ++t) {
                float p = fmaxf(e1p * p2a[t], e1n * n2a[t]);
                p = ((wb >> (q * 8 + t)) & 1u) ? p : 0.f;
                rs += p;
                af[t] = (bf16)p;
            }
            #pragma unroll
            for (int t = 0; t < 4; ++t) {
                float p = fmaxf(e1p * p2b[t], e1n * n2b[t]);
                p = ((wb >> (q * 8 + 4 + t)) & 1u) ? p : 0.f;
                rs += p;
                af[4 + t] = (bf16)p;
            }

            const bf16* pbs = pb + (size_t)(j >> 5) * 4096;
            #pragma unroll
            for (int t = 0; t < 8; ++t) {
                const bf16x8 b = __builtin_bit_cast(bf16x8, *(const u32x4*)(pbs + t * 512));
                acc[t] = __builtin_amdgcn_mfma_f32_16x16x32_bf16(af, b, acc[t], 0, 0, 0);
            }
        }
    }

    // row-sum: lanes {m, m+16, m+32, m+48} hold the 4 q-slices of row m
    rs += __shfl_xor(rs, 16);
    rs += __shfl_xor(rs, 32);
    if (lane < 16) denP[(size_t)jc * NN + rbase + m] = rs;

    // C/D layout: col = lane&15, row = q*4 + r -> unique partial slot
    #pragma unroll
    for (int t = 0; t < 8; ++t)
        #pragma unroll
        for (int r = 0; r < 4; ++r)
            numP[((size_t)jc * NN + rbase + q * 4 + r) * OUTF + t * 16 + m] = acc[t][r];
}

// ---------------------------------------------------------------------------
// Finalize: out = elu( (sum_s numP) / (sum_s denP) ), fp32 out.
// ---------------------------------------------------------------------------
__global__ __launch_bounds__(256)
void gat_fin(const float* __restrict__ numP, const float* __restrict__ denP,
             float* __restrict__ outv)
{
    const int g  = blockIdx.x * 256 + threadIdx.x;   // one thread per 4 elems
    const int i  = g >> 5;
    const int c4 = g & 31;
    float d = 0.f;
    f32x4 v = {0.f, 0.f, 0.f, 0.f};
    #pragma unroll
    for (int s = 0; s < JSPLIT; ++s) {
        d += denP[(size_t)s * NN + i];
        const f32x4 u = *(const f32x4*)(numP + ((size_t)s * NN + i) * OUTF + c4 * 4);
        #pragma unroll
        for (int t = 0; t < 4; ++t) v[t] += u[t];
    }
    #pragma unroll
    for (int t = 0; t < 4; ++t) {
        const float u = v[t] / d;
        v[t] = (u > 0.f) ? u : __builtin_amdgcn_exp2f(u * LOG2E) - 1.f;  // elu
    }
    *(f32x4*)(outv + (size_t)i * OUTF + c4 * 4) = v;
}

// ---------------------------------------------------------------------------
extern "C" void kernel_launch(void* const* d_in, const int* in_sizes, int n_in,
                              void* d_out, int out_size, void* d_ws, size_t ws_size,
                              hipStream_t stream)
{
    const float* x     = (const float*)d_in[0];
    const int*   adj   = (const int*)d_in[1];
    const float* trans = (const float*)d_in[2];
    const float* aw    = (const float*)d_in[3];

    // ws layout (bytes):
    // HTt 2MB | E1p/E1n/E2p/E2n 4x32KB | TT 64KB | numP 32MB | denP 256KB
    char* w = (char*)d_ws;
    bf16*  HTt  = (bf16*)w;   w += (size_t)OUTF * NN * 2;
    float* E1p  = (float*)w;  w += NN * 4;
    float* E1n  = (float*)w;  w += NN * 4;
    float* E2p  = (float*)w;  w += NN * 4;
    float* E2n  = (float*)w;  w += NN * 4;
    bf16*  TT   = (bf16*)w;   w += (size_t)OUTF * INF_ * 2;
    float* numP = (float*)w;  w += (size_t)JSPLIT * NN * OUTF * 4;
    float* denP = (float*)w;

    gat_tt<<<OUTF, INF_, 0, stream>>>(trans, TT);

    gat_proj<<<NN / 16, 256, 0, stream>>>(x, TT, aw, HTt, E1p, E1n, E2p, E2n);

    gat_attn<<<(NN / 64) * JSPLIT, 256, 0, stream>>>(adj, HTt, E1p, E1n, E2p, E2n,
                                                     numP, denP);

    gat_fin<<<NN * OUTF / 4 / 256, 256, 0, stream>>>(numP, denP, (float*)d_out);
}